// Round 2
// baseline (1474.087 us; speedup 1.0000x reference)
//
#include <hip/hip_runtime.h>
#include <hip/hip_bf16.h>

typedef unsigned short u16;
typedef unsigned long long u64;
typedef float f32x2 __attribute__((ext_vector_type(2)));

#define NN 4096
#define SS 1024
#define NSAMP 32
#define NGRP 16384            // 16*1024 groups
#define ROWS 524288           // NGRP*NSAMP
#define BN_EPS_F 1e-5f
#define INV_ROWS (1.0f/524288.0f)

// ---------------- packed fp32 helpers (VOP3P, gfx90a+) ----------------
// Each half rounds independently -> bitwise identical to scalar __fadd_rn/__fmul_rn.
__device__ __forceinline__ f32x2 pk_add(f32x2 a, f32x2 b){
    f32x2 d; asm("v_pk_add_f32 %0, %1, %2" : "=v"(d) : "v"(a), "v"(b)); return d;
}
__device__ __forceinline__ f32x2 pk_mul(f32x2 a, f32x2 b){
    f32x2 d; asm("v_pk_mul_f32 %0, %1, %2" : "=v"(d) : "v"(a), "v"(b)); return d;
}

// ---------------- FPS v8: 512 thr (2 waves/SIMD latency hiding) + pk-f32 ----------------
// v7 (256thr) was 1553 cyc/iter with ~470 issue + ~1000 exposed latency (1 wave/SIMD:
// every LDS round-trip and the DPP hazard chain fully serialized). v8: packed-f32
// halves distance-update issue; 2nd wave/SIMD hides the serial-chain latency.
// Key = (distbits<<32)|(NN-1-idx): exact argmax with first-index tie-break.
#define FPS_DPP_STEP(CTRL)                                                              \
    {   int hs = __builtin_amdgcn_update_dpp((int)(bk >> 32), (int)(bk >> 32),          \
                                             CTRL, 0xf, 0xf, false);                    \
        int ls = __builtin_amdgcn_update_dpp((int)bk, (int)bk, CTRL, 0xf, 0xf, false);  \
        u64 o = ((u64)(unsigned int)hs << 32) | (unsigned int)ls;                       \
        bk = bk > o ? bk : o; }

__global__ __launch_bounds__(512, 1) void fps_kernel(const float* __restrict__ xyz,
                                                     float* __restrict__ out,
                                                     float* __restrict__ stats){
    __shared__ float xs[NN], ys[NN], zs[NN];
    __shared__ u64 red[2][8];
    const int b = blockIdx.x;
    const int tid = threadIdx.x;
    if (b == 0) stats[tid] = 0.0f;     // folded zero_kernel (512 floats, consumed later)
    const float* xb = xyz + (size_t)b * NN * 3;
    f32x2 px2[4], py2[4], pz2[4], d2[4];
    unsigned int inv[8];
    #pragma unroll
    for (int q = 0; q < 4; ++q){
        int i0 = tid + (2*q)   * 512;
        int i1 = tid + (2*q+1) * 512;
        float x0 = xb[i0*3+0], y0 = xb[i0*3+1], z0 = xb[i0*3+2];
        float x1 = xb[i1*3+0], y1 = xb[i1*3+1], z1 = xb[i1*3+2];
        px2[q].x = x0; px2[q].y = x1;
        py2[q].x = y0; py2[q].y = y1;
        pz2[q].x = z0; pz2[q].y = z1;
        xs[i0] = x0; ys[i0] = y0; zs[i0] = z0;
        xs[i1] = x1; ys[i1] = y1; zs[i1] = z1;
        d2[q].x = 1e10f; d2[q].y = 1e10f;          // ref init 1e10 (exact f32)
        inv[2*q]   = (unsigned int)(NN - 1 - i0);  // loop-invariant key low words
        inv[2*q+1] = (unsigned int)(NN - 1 - i1);
    }
    int cur = 0;
    __syncthreads();
    if (tid == 0){  // fps_idx[b,0] == 0 (scan emits carry before update)
        float* of = out + (size_t)b * SS * 3;
        of[0] = xs[0]; of[1] = ys[0]; of[2] = zs[0];
    }
    const int wave = tid >> 6, lane = tid & 63;
    for (int it = 1; it < SS; ++it){
        float cx = xs[cur], cy = ys[cur], cz = zs[cur];   // uniform LDS broadcast
        // a + (-c) is IEEE-identical to a - c; broadcast negated centroid once
        float nx = -cx, ny = -cy, nz = -cz;
        f32x2 ncx; ncx.x = nx; ncx.y = nx;
        f32x2 ncy; ncy.x = ny; ncy.y = ny;
        f32x2 ncz; ncz.x = nz; ncz.y = nz;
        u64 t8[8];
        // strict fp32 order: ((dx*dx + dy*dy) + dz*dz), each op rounds separately
        #pragma unroll
        for (int q = 0; q < 4; ++q){
            f32x2 dx = pk_add(px2[q], ncx);
            f32x2 dy = pk_add(py2[q], ncy);
            f32x2 dz = pk_add(pz2[q], ncz);
            f32x2 xx = pk_mul(dx, dx);
            f32x2 yy = pk_mul(dy, dy);
            f32x2 ss = pk_add(xx, yy);
            f32x2 zz = pk_mul(dz, dz);
            f32x2 dd = pk_add(ss, zz);
            d2[q].x = fminf(d2[q].x, dd.x);
            d2[q].y = fminf(d2[q].y, dd.y);
            t8[2*q]   = ((u64)__float_as_uint(d2[q].x) << 32) | inv[2*q];
            t8[2*q+1] = ((u64)__float_as_uint(d2[q].y) << 32) | inv[2*q+1];
        }
        // pairwise tree (ILP)
        #pragma unroll
        for (int s = 4; s >= 1; s >>= 1)
            #pragma unroll
            for (int i2 = 0; i2 < s; ++i2)
                if (t8[i2 + s] > t8[i2]) t8[i2] = t8[i2 + s];
        u64 bk = t8[0];
        // DPP reduce over 64 lanes -> winner at lane 63 (VALU pipe, no DS latency)
        FPS_DPP_STEP(0x111)  // row_shr:1
        FPS_DPP_STEP(0x112)  // row_shr:2
        FPS_DPP_STEP(0x114)  // row_shr:4
        FPS_DPP_STEP(0x118)  // row_shr:8  -> lane15 of each row = row max
        FPS_DPP_STEP(0x142)  // row_bcast:15 -> lane31/63 accumulate halves
        FPS_DPP_STEP(0x143)  // row_bcast:31 -> lane63 = wave max
        unsigned int wh = (unsigned int)__builtin_amdgcn_readlane((int)(bk >> 32), 63);
        unsigned int wl = (unsigned int)__builtin_amdgcn_readlane((int)bk, 63);
        if (lane == 0) red[it & 1][wave] = ((u64)wh << 32) | wl;
        __syncthreads();                       // double-buffered red: one barrier/iter
        u64 m[8];
        #pragma unroll
        for (int w = 0; w < 8; ++w) m[w] = red[it & 1][w];
        #pragma unroll
        for (int s = 4; s >= 1; s >>= 1)
            #pragma unroll
            for (int i2 = 0; i2 < s; ++i2)
                if (m[i2 + s] > m[i2]) m[i2] = m[i2 + s];
        cur = (NN - 1 - (int)(m[0] & 0xffffffffu)) & (NN - 1);
        if (tid == 0){
            float* of = out + ((size_t)b * SS + it) * 3;
            of[0] = xs[cur]; of[1] = ys[cur]; of[2] = zs[cur];
        }
    }
}

// ---------------- ball query v3: 512-pt super-chunks, pipelined masks ----------------
__global__ __launch_bounds__(256) void ballq_kernel(const float* __restrict__ xyz,
                                                    const float* __restrict__ outc,
                                                    u16* __restrict__ gidx){
    const int g = (blockIdx.x << 2) + (threadIdx.x >> 6);
    const int lane = threadIdx.x & 63;
    const int b = g >> 10;
    const float rr = 0.04f;   // np.float32 promotion of python 0.2*0.2
    const float* c = outc + (size_t)g * 3;
    float cx = c[0], cy = c[1], cz = c[2];
    float sa = __fadd_rn(__fadd_rn(__fmul_rn(cx,cx), __fmul_rn(cy,cy)), __fmul_rn(cz,cz));
    const float* xb = xyz + (size_t)b * NN * 3;
    u16* outp = gidx + (size_t)g * NSAMP;
    int count = 0, first = -1;
    const u64 below = (1ull << lane) - 1ull;
    for (int base = 0; base < NN && count < NSAMP; base += 512){
        u64 masks[8];
        #pragma unroll
        for (int u = 0; u < 8; ++u){          // 8 independent distance+ballot: loads pipeline
            int n = base + u * 64 + lane;
            float x = xb[n*3+0], y = xb[n*3+1], z = xb[n*3+2];
            float sb = __fadd_rn(__fadd_rn(__fmul_rn(x,x), __fmul_rn(y,y)), __fmul_rn(z,z));
            float dt = __fadd_rn(__fadd_rn(__fmul_rn(cx,x), __fmul_rn(cy,y)), __fmul_rn(cz,z));
            float sq = __fadd_rn(__fsub_rn(sa, __fmul_rn(2.0f, dt)), sb);
            masks[u] = __ballot(!(sq > rr));
        }
        #pragma unroll
        for (int u = 0; u < 8; ++u){          // append phase: VALU-only serial chain
            u64 m = masks[u];
            bool w = (m >> lane) & 1ull;
            int pos = __popcll(m & below);
            if (w && (count + pos) < NSAMP) outp[count + pos] = (u16)(base + u * 64 + lane);
            if (first < 0 && m != 0ull) first = base + u * 64 + (__ffsll((long long)m) - 1);
            count += __popcll(m);
        }
    }
    for (int j = count + lane; j < NSAMP; j += 64) outp[j] = (u16)first;
}

// ---------------- shared helpers ----------------
__device__ __forceinline__ void gather_row(const float* __restrict__ xyz, const float* __restrict__ pts,
                                           const float* __restrict__ outc, const u16* __restrict__ gidx,
                                           int row, float* x){
    int g = row >> 5;
    int b = row >> 15;
    int i = gidx[row];
    const float* cc = outc + (size_t)g * 3;
    const float* xp = xyz + ((size_t)b * NN + i) * 3;
    const float* pp = pts + ((size_t)b * NN + i) * 6;
    x[0] = __fsub_rn(xp[0], cc[0]);
    x[1] = __fsub_rn(xp[1], cc[1]);
    x[2] = __fsub_rn(xp[2], cc[2]);
    #pragma unroll
    for (int k = 0; k < 6; ++k) x[3+k] = pp[k];
}

__device__ __forceinline__ void bn_coef(const float* sums, const float* ssqs,
                                        const float* g, const float* bbv, int ch,
                                        float* sc, float* sh){
    float mu = sums[ch] * INV_ROWS;
    float var = fmaf(-mu, mu, ssqs[ch] * INV_ROWS);
    var = fmaxf(var, 0.0f);
    float is = rsqrtf(var + BN_EPS_F);
    float s = is * g[ch];
    sc[ch] = s;
    sh[ch] = fmaf(-mu, s, bbv[ch]);
}

// ---------------- stats1 v2: one row/thread + LDS-transpose reduce ----------------
__global__ __launch_bounds__(256, 1) void stats1_kernel(const float* __restrict__ xyz, const float* __restrict__ pts,
                                                        const float* __restrict__ outc, const u16* __restrict__ gidx,
                                                        const float* __restrict__ W0f, const float* __restrict__ b0f,
                                                        float* __restrict__ stats){
    __shared__ float tr[256 * 65];
    __shared__ float accs[4][64], accq[4][64];
    const int row = blockIdx.x * 256 + threadIdx.x;
    float x[9];
    gather_row(xyz, pts, outc, gidx, row, x);
    #pragma unroll
    for (int j = 0; j < 64; ++j){
        float acc = b0f[j];
        #pragma unroll
        for (int k = 0; k < 9; ++k) acc = fmaf(x[k], W0f[j*9+k], acc);
        tr[threadIdx.x * 65 + j] = acc;
    }
    __syncthreads();
    const int ch = threadIdx.x & 63, qq = threadIdx.x >> 6;
    float s = 0.f, q = 0.f;
    for (int r = 0; r < 64; ++r){
        float v = tr[(qq * 64 + r) * 65 + ch];
        s += v; q = fmaf(v, v, q);
    }
    accs[qq][ch] = s; accq[qq][ch] = q;
    __syncthreads();
    if (threadIdx.x < 64){
        int c = threadIdx.x;
        atomicAdd(&stats[c], (accs[0][c] + accs[1][c]) + (accs[2][c] + accs[3][c]));
    } else if (threadIdx.x < 128){
        int c = threadIdx.x - 64;
        atomicAdd(&stats[64 + c], (accq[0][c] + accq[1][c]) + (accq[2][c] + accq[3][c]));
    }
}

// ---------------- stats2: transpose reduce + (256,1) ----------------
__global__ __launch_bounds__(256, 1) void stats2_kernel(const float* __restrict__ xyz, const float* __restrict__ pts,
                                                        const float* __restrict__ outc, const u16* __restrict__ gidx,
                                                        const float* __restrict__ W0f, const float* __restrict__ b0f,
                                                        const float* __restrict__ W1f, const float* __restrict__ b1f,
                                                        const float* __restrict__ g0, const float* __restrict__ bb0,
                                                        float* __restrict__ stats){
    __shared__ float sc1[64], sh1[64];
    __shared__ float tr[256 * 65];
    __shared__ float accs[4][64], accq[4][64];
    if (threadIdx.x < 64) bn_coef(stats + 0, stats + 64, g0, bb0, threadIdx.x, sc1, sh1);
    __syncthreads();
    const int row = blockIdx.x * 256 + threadIdx.x;
    float x[9];
    gather_row(xyz, pts, outc, gidx, row, x);
    float x2[64];
    #pragma unroll
    for (int j = 0; j < 64; ++j){
        float acc = b0f[j];
        #pragma unroll
        for (int k = 0; k < 9; ++k) acc = fmaf(x[k], W0f[j*9+k], acc);
        x2[j] = fmaxf(fmaf(acc, sc1[j], sh1[j]), 0.f);
    }
    for (int ch = 0; ch < 64; ++ch){
        float a0 = b1f[ch], a1 = 0.f, a2 = 0.f, a3 = 0.f;
        const float* wrow = W1f + ch * 64;
        #pragma unroll
        for (int k = 0; k < 64; k += 4){
            a0 = fmaf(x2[k+0], wrow[k+0], a0);
            a1 = fmaf(x2[k+1], wrow[k+1], a1);
            a2 = fmaf(x2[k+2], wrow[k+2], a2);
            a3 = fmaf(x2[k+3], wrow[k+3], a3);
        }
        tr[threadIdx.x * 65 + ch] = (a0 + a1) + (a2 + a3);
    }
    __syncthreads();
    const int ch = threadIdx.x & 63, qq = threadIdx.x >> 6;
    float s = 0.f, q = 0.f;
    for (int r = 0; r < 64; ++r){
        float v = tr[(qq * 64 + r) * 65 + ch];
        s += v; q = fmaf(v, v, q);
    }
    accs[qq][ch] = s; accq[qq][ch] = q;
    __syncthreads();
    if (threadIdx.x < 64){
        int c = threadIdx.x;
        atomicAdd(&stats[128 + c], (accs[0][c] + accs[1][c]) + (accs[2][c] + accs[3][c]));
    } else if (threadIdx.x < 128){
        int c = threadIdx.x - 64;
        atomicAdd(&stats[192 + c], (accq[0][c] + accq[1][c]) + (accq[2][c] + accq[3][c]));
    }
}

// ---------------- stats3 v2: x3 staged through LDS to kill the x2/x3 dual-liveness ----------------
__global__ __launch_bounds__(256, 1) void stats3_kernel(const float* __restrict__ xyz, const float* __restrict__ pts,
                                                        const float* __restrict__ outc, const u16* __restrict__ gidx,
                                                        const float* __restrict__ W0f, const float* __restrict__ b0f,
                                                        const float* __restrict__ W1f, const float* __restrict__ b1f,
                                                        const float* __restrict__ W2f, const float* __restrict__ b2f,
                                                        const float* __restrict__ g0, const float* __restrict__ bb0,
                                                        const float* __restrict__ g1, const float* __restrict__ bb1,
                                                        float* __restrict__ stats,
                                                        float* __restrict__ pmax, float* __restrict__ pmin){
    __shared__ float sc1[64], sh1[64], sc2[64], sh2[64];
    __shared__ float tr[256 * 65];
    __shared__ float accs[4][64], accq[4][64];
    if (threadIdx.x < 64){
        bn_coef(stats + 0,   stats + 64,  g0, bb0, threadIdx.x, sc1, sh1);
        bn_coef(stats + 128, stats + 192, g1, bb1, threadIdx.x, sc2, sh2);
    }
    __syncthreads();
    const int row = blockIdx.x * 256 + threadIdx.x;
    float x[9];
    gather_row(xyz, pts, outc, gidx, row, x);
    float x2[64];
    #pragma unroll
    for (int j = 0; j < 64; ++j){
        float acc = b0f[j];
        #pragma unroll
        for (int k = 0; k < 9; ++k) acc = fmaf(x[k], W0f[j*9+k], acc);
        x2[j] = fmaxf(fmaf(acc, sc1[j], sh1[j]), 0.f);
    }
    // phase B: x3[j] -> LDS (own row, no barrier needed: same-thread RAW)
    #pragma unroll
    for (int j = 0; j < 64; ++j){
        float a0 = b1f[j], a1 = 0.f, a2 = 0.f, a3 = 0.f;
        const float* wrow = W1f + j * 64;
        #pragma unroll
        for (int k = 0; k < 64; k += 4){
            a0 = fmaf(x2[k+0], wrow[k+0], a0);
            a1 = fmaf(x2[k+1], wrow[k+1], a1);
            a2 = fmaf(x2[k+2], wrow[k+2], a2);
            a3 = fmaf(x2[k+3], wrow[k+3], a3);
        }
        tr[threadIdx.x * 65 + j] = fmaxf(fmaf((a0 + a1) + (a2 + a3), sc2[j], sh2[j]), 0.f);
    }
    // compiler barrier: forbid store-to-load forwarding of the staged x3 (which
    // would resurrect the x2+x3 dual-liveness and the spills)
    asm volatile("" ::: "memory");
    float x3[64];
    #pragma unroll
    for (int j = 0; j < 64; ++j) x3[j] = tr[threadIdx.x * 65 + j];
    const int ch = threadIdx.x & 63, qq = threadIdx.x >> 6;
    for (int half = 0; half < 2; ++half){
        for (int c64 = 0; c64 < 64; ++c64){
            int c = half * 64 + c64;
            float a0 = b2f[c], a1 = 0.f, a2 = 0.f, a3 = 0.f;
            const float* wrow = W2f + c * 64;
            #pragma unroll
            for (int k = 0; k < 64; k += 4){
                a0 = fmaf(x3[k+0], wrow[k+0], a0);
                a1 = fmaf(x3[k+1], wrow[k+1], a1);
                a2 = fmaf(x3[k+2], wrow[k+2], a2);
                a3 = fmaf(x3[k+3], wrow[k+3], a3);
            }
            tr[threadIdx.x * 65 + c64] = (a0 + a1) + (a2 + a3);
        }
        __syncthreads();
        // quarter qq = rows [qq*64, qq*64+64) = groups 2qq (first 32 rows) and 2qq+1
        float s = 0.f, q = 0.f;
        float mxA = -1e30f, mnA = 1e30f, mxB = -1e30f, mnB = 1e30f;
        for (int r = 0; r < 32; ++r){
            float v = tr[(qq * 64 + r) * 65 + ch];
            s += v; q = fmaf(v, v, q);
            mxA = fmaxf(mxA, v); mnA = fminf(mnA, v);
        }
        for (int r = 32; r < 64; ++r){
            float v = tr[(qq * 64 + r) * 65 + ch];
            s += v; q = fmaf(v, v, q);
            mxB = fmaxf(mxB, v); mnB = fminf(mnB, v);
        }
        int c = half * 64 + ch;
        int gA = blockIdx.x * 8 + 2 * qq;
        pmax[(size_t)gA * 128 + c] = mxA;           // coalesced across lanes (c consecutive)
        pmin[(size_t)gA * 128 + c] = mnA;
        pmax[(size_t)(gA + 1) * 128 + c] = mxB;
        pmin[(size_t)(gA + 1) * 128 + c] = mnB;
        accs[qq][ch] = s; accq[qq][ch] = q;
        __syncthreads();
        if (threadIdx.x < 64){
            int cc = half * 64 + threadIdx.x;
            atomicAdd(&stats[256 + cc], (accs[0][threadIdx.x] + accs[1][threadIdx.x])
                                      + (accs[2][threadIdx.x] + accs[3][threadIdx.x]));
        } else if (threadIdx.x < 128){
            int t = threadIdx.x - 64;
            int cc = half * 64 + t;
            atomicAdd(&stats[384 + cc], (accq[0][t] + accq[1][t]) + (accq[2][t] + accq[3][t]));
        }
        __syncthreads();   // tr + accs reuse protection for next half
    }
}

// ---------------- BN3 applied to group max/min, relu, write out region 1 (f32) ----------------
__global__ __launch_bounds__(256) void pool_kernel(const float* __restrict__ stats,
                                                   const float* __restrict__ g2, const float* __restrict__ bb2,
                                                   const float* __restrict__ pmax, const float* __restrict__ pmin,
                                                   float* __restrict__ out){
    __shared__ float sc[128], sh[128];
    if (threadIdx.x < 128) bn_coef(stats + 256, stats + 384, g2, bb2, threadIdx.x, sc, sh);
    __syncthreads();
    int o = blockIdx.x * 256 + threadIdx.x;   // o = g*128 + ch, o < NGRP*128
    int ch = o & 127;
    float a = fmaf(pmax[o], sc[ch], sh[ch]);
    float b = fmaf(pmin[o], sc[ch], sh[ch]);  // affine maps interval endpoints (sc<0 covered)
    out[NGRP * 3 + o] = fmaxf(fmaxf(a, b), 0.0f);
}

extern "C" void kernel_launch(void* const* d_in, const int* in_sizes, int n_in,
                              void* d_out, int out_size, void* d_ws, size_t ws_size,
                              hipStream_t stream){
    const float* xyz = (const float*)d_in[0];
    const float* pts = (const float*)d_in[1];
    const float* W0  = (const float*)d_in[2];
    const float* b0  = (const float*)d_in[3];
    const float* g0  = (const float*)d_in[4];
    const float* bb0 = (const float*)d_in[5];
    const float* W1  = (const float*)d_in[6];
    const float* b1  = (const float*)d_in[7];
    const float* g1  = (const float*)d_in[8];
    const float* bb1 = (const float*)d_in[9];
    const float* W2  = (const float*)d_in[10];
    const float* b2  = (const float*)d_in[11];
    const float* g2  = (const float*)d_in[12];
    const float* bb2 = (const float*)d_in[13];
    float* out = (float*)d_out;   // f32 outputs: [new_xyz 49152 | new_points 2097152]

    // ws layout (bytes): stats[512f]@0 | gidx[524288 u16]@2048 |
    //                    pmax[2097152f]@1050624 | pmin@9439232 ; total 17,827,840
    if (ws_size < 17827840u) return;
    char*  ws    = (char*)d_ws;
    float* stats = (float*)ws;
    u16*   gidx  = (u16*)  (ws + 2048);
    float* pmax  = (float*)(ws + 1050624);
    float* pmin  = (float*)(ws + 9439232);

    fps_kernel  <<<16, 512, 0, stream>>>(xyz, out, stats);   // block 0 also zeroes stats
    ballq_kernel<<<NGRP/4, 256, 0, stream>>>(xyz, out, gidx);
    stats1_kernel<<<ROWS/256, 256, 0, stream>>>(xyz, pts, out, gidx, W0, b0, stats);
    stats2_kernel<<<ROWS/256, 256, 0, stream>>>(xyz, pts, out, gidx, W0, b0, W1, b1, g0, bb0, stats);
    stats3_kernel<<<ROWS/256, 256, 0, stream>>>(xyz, pts, out, gidx, W0, b0, W1, b1, W2, b2,
                                                g0, bb0, g1, bb1, stats, pmax, pmin);
    pool_kernel <<<NGRP*128/256, 256, 0, stream>>>(stats, g2, bb2, pmax, pmin, out);
}

// Round 3
// 1270.666 us; speedup vs baseline: 1.1601x; 1.1601x over previous
//
#include <hip/hip_runtime.h>
#include <hip/hip_bf16.h>

typedef unsigned short u16;
typedef unsigned long long u64;
typedef float f32x2 __attribute__((ext_vector_type(2)));

#define NN 4096
#define SS 1024
#define NSAMP 32
#define NGRP 16384            // 16*1024 groups
#define ROWS 524288           // NGRP*NSAMP
#define BN_EPS_F 1e-5f
#define INV_ROWS (1.0f/524288.0f)

// ---------------- packed fp32 FMA (VOP3P, full-rate fp32 path on CDNA) ----------------
// Each half is a full-precision FMA -> bitwise identical to scalar fmaf per lane-half.
__device__ __forceinline__ f32x2 pk_fma(f32x2 a, f32x2 b, f32x2 c){
    f32x2 d; asm("v_pk_fma_f32 %0, %1, %2, %3" : "=v"(d) : "v"(a), "v"(b), "v"(c)); return d;
}

// ---------------- FPS v7 revert (known 662us): 256 thr, scalar strict fp32 ----------------
// R2 post-mortem: 512thr regressed (+81us) -- iterations are strictly serial through the
// barrier publishing `cur`, so extra waves only add rendezvous skew + duplicated reduce
// overhead. v7 structure restored verbatim; block 0 additionally zeroes stats (one less
// launch). Key = (distbits<<32)|(NN-1-idx): exact argmax with first-index tie-break.
#define FPS_DPP_STEP(CTRL)                                                              \
    {   int hs = __builtin_amdgcn_update_dpp((int)(bk >> 32), (int)(bk >> 32),          \
                                             CTRL, 0xf, 0xf, false);                    \
        int ls = __builtin_amdgcn_update_dpp((int)bk, (int)bk, CTRL, 0xf, 0xf, false);  \
        u64 o = ((u64)(unsigned int)hs << 32) | (unsigned int)ls;                       \
        bk = bk > o ? bk : o; }

__global__ __launch_bounds__(256, 1) void fps_kernel(const float* __restrict__ xyz,
                                                     float* __restrict__ out,
                                                     float* __restrict__ stats){
    __shared__ float xs[NN], ys[NN], zs[NN];
    __shared__ u64 red[2][4];
    const int b = blockIdx.x;
    const int tid = threadIdx.x;
    if (b == 0){ stats[tid] = 0.0f; stats[tid + 256] = 0.0f; }   // folded zero_kernel
    const float* xb = xyz + (size_t)b * NN * 3;
    float px[16], py[16], pz[16], dreg[16];
    unsigned int inv[16];
    #pragma unroll
    for (int p = 0; p < 16; ++p){
        int i = tid + p * 256;
        float x = xb[i*3+0], y = xb[i*3+1], z = xb[i*3+2];
        px[p] = x; py[p] = y; pz[p] = z;
        xs[i] = x; ys[i] = y; zs[i] = z;
        dreg[p] = 1e10f;                      // ref init 1e10 (exact f32)
        inv[p] = (unsigned int)(NN - 1 - i);  // loop-invariant key low word
    }
    int cur = 0;
    __syncthreads();
    if (tid == 0){  // fps_idx[b,0] == 0 (scan emits carry before update)
        float* of = out + (size_t)b * SS * 3;
        of[0] = xs[0]; of[1] = ys[0]; of[2] = zs[0];
    }
    const int wave = tid >> 6, lane = tid & 63;
    for (int it = 1; it < SS; ++it){
        float cx = xs[cur], cy = ys[cur], cz = zs[cur];   // uniform LDS broadcast
        u64 t[16];
        // strict fp32, no fma contraction: must match numpy's ((dx*dx+dy*dy)+dz*dz) bitwise
        #pragma unroll
        for (int p = 0; p < 16; ++p){
            float dx = __fsub_rn(px[p], cx);
            float dy = __fsub_rn(py[p], cy);
            float dz = __fsub_rn(pz[p], cz);
            float dd = __fadd_rn(__fadd_rn(__fmul_rn(dx,dx), __fmul_rn(dy,dy)),
                                 __fmul_rn(dz,dz));
            dreg[p] = fminf(dreg[p], dd);
            t[p] = ((u64)__float_as_uint(dreg[p]) << 32) | inv[p];
        }
        // pairwise tree (ILP) instead of serial 16-deep chain
        #pragma unroll
        for (int s = 8; s >= 1; s >>= 1)
            #pragma unroll
            for (int i2 = 0; i2 < s; ++i2)
                if (t[i2 + s] > t[i2]) t[i2] = t[i2 + s];
        u64 bk = t[0];
        // DPP reduce over 64 lanes -> winner at lane 63 (VALU pipe, no DS latency)
        FPS_DPP_STEP(0x111)  // row_shr:1
        FPS_DPP_STEP(0x112)  // row_shr:2
        FPS_DPP_STEP(0x114)  // row_shr:4
        FPS_DPP_STEP(0x118)  // row_shr:8  -> lane15 of each row = row max
        FPS_DPP_STEP(0x142)  // row_bcast:15 -> lane31/63 accumulate halves
        FPS_DPP_STEP(0x143)  // row_bcast:31 -> lane63 = wave max
        unsigned int wh = (unsigned int)__builtin_amdgcn_readlane((int)(bk >> 32), 63);
        unsigned int wl = (unsigned int)__builtin_amdgcn_readlane((int)bk, 63);
        if (lane == 0) red[it & 1][wave] = ((u64)wh << 32) | wl;
        __syncthreads();                       // double-buffered red: one barrier/iter
        u64 m0 = red[it & 1][0];
        #pragma unroll
        for (int w = 1; w < 4; ++w){
            u64 o = red[it & 1][w];
            m0 = m0 > o ? m0 : o;
        }
        cur = (NN - 1 - (int)(m0 & 0xffffffffu)) & (NN - 1);
        if (tid == 0){
            float* of = out + ((size_t)b * SS + it) * 3;
            of[0] = xs[cur]; of[1] = ys[cur]; of[2] = zs[cur];
        }
    }
}

// ---------------- ball query v3: 512-pt super-chunks, pipelined masks ----------------
__global__ __launch_bounds__(256) void ballq_kernel(const float* __restrict__ xyz,
                                                    const float* __restrict__ outc,
                                                    u16* __restrict__ gidx){
    const int g = (blockIdx.x << 2) + (threadIdx.x >> 6);
    const int lane = threadIdx.x & 63;
    const int b = g >> 10;
    const float rr = 0.04f;   // np.float32 promotion of python 0.2*0.2
    const float* c = outc + (size_t)g * 3;
    float cx = c[0], cy = c[1], cz = c[2];
    float sa = __fadd_rn(__fadd_rn(__fmul_rn(cx,cx), __fmul_rn(cy,cy)), __fmul_rn(cz,cz));
    const float* xb = xyz + (size_t)b * NN * 3;
    u16* outp = gidx + (size_t)g * NSAMP;
    int count = 0, first = -1;
    const u64 below = (1ull << lane) - 1ull;
    for (int base = 0; base < NN && count < NSAMP; base += 512){
        u64 masks[8];
        #pragma unroll
        for (int u = 0; u < 8; ++u){          // 8 independent distance+ballot: loads pipeline
            int n = base + u * 64 + lane;
            float x = xb[n*3+0], y = xb[n*3+1], z = xb[n*3+2];
            float sb = __fadd_rn(__fadd_rn(__fmul_rn(x,x), __fmul_rn(y,y)), __fmul_rn(z,z));
            float dt = __fadd_rn(__fadd_rn(__fmul_rn(cx,x), __fmul_rn(cy,y)), __fmul_rn(cz,z));
            float sq = __fadd_rn(__fsub_rn(sa, __fmul_rn(2.0f, dt)), sb);
            masks[u] = __ballot(!(sq > rr));
        }
        #pragma unroll
        for (int u = 0; u < 8; ++u){          // append phase: VALU-only serial chain
            u64 m = masks[u];
            bool w = (m >> lane) & 1ull;
            int pos = __popcll(m & below);
            if (w && (count + pos) < NSAMP) outp[count + pos] = (u16)(base + u * 64 + lane);
            if (first < 0 && m != 0ull) first = base + u * 64 + (__ffsll((long long)m) - 1);
            count += __popcll(m);
        }
    }
    for (int j = count + lane; j < NSAMP; j += 64) outp[j] = (u16)first;
}

// ---------------- shared helpers ----------------
__device__ __forceinline__ void gather_row(const float* __restrict__ xyz, const float* __restrict__ pts,
                                           const float* __restrict__ outc, const u16* __restrict__ gidx,
                                           int row, float* x){
    int g = row >> 5;
    int b = row >> 15;
    int i = gidx[row];
    const float* cc = outc + (size_t)g * 3;
    const float* xp = xyz + ((size_t)b * NN + i) * 3;
    const float* pp = pts + ((size_t)b * NN + i) * 6;
    x[0] = __fsub_rn(xp[0], cc[0]);
    x[1] = __fsub_rn(xp[1], cc[1]);
    x[2] = __fsub_rn(xp[2], cc[2]);
    #pragma unroll
    for (int k = 0; k < 6; ++k) x[3+k] = pp[k];
}

__device__ __forceinline__ void bn_coef(const float* sums, const float* ssqs,
                                        const float* g, const float* bbv, int ch,
                                        float* sc, float* sh){
    float mu = sums[ch] * INV_ROWS;
    float var = fmaf(-mu, mu, ssqs[ch] * INV_ROWS);
    var = fmaxf(var, 0.0f);
    float is = rsqrtf(var + BN_EPS_F);
    float s = is * g[ch];
    sc[ch] = s;
    sh[ch] = fmaf(-mu, s, bbv[ch]);
}

// ---------------- stats1 v2: one row/thread + LDS-transpose reduce ----------------
__global__ __launch_bounds__(256, 1) void stats1_kernel(const float* __restrict__ xyz, const float* __restrict__ pts,
                                                        const float* __restrict__ outc, const u16* __restrict__ gidx,
                                                        const float* __restrict__ W0f, const float* __restrict__ b0f,
                                                        float* __restrict__ stats){
    __shared__ float tr[256 * 65];
    __shared__ float accs[4][64], accq[4][64];
    const int row = blockIdx.x * 256 + threadIdx.x;
    float x[9];
    gather_row(xyz, pts, outc, gidx, row, x);
    #pragma unroll
    for (int j = 0; j < 64; ++j){
        float acc = b0f[j];
        #pragma unroll
        for (int k = 0; k < 9; ++k) acc = fmaf(x[k], W0f[j*9+k], acc);
        tr[threadIdx.x * 65 + j] = acc;
    }
    __syncthreads();
    const int ch = threadIdx.x & 63, qq = threadIdx.x >> 6;
    float s = 0.f, q = 0.f;
    for (int r = 0; r < 64; ++r){
        float v = tr[(qq * 64 + r) * 65 + ch];
        s += v; q = fmaf(v, v, q);
    }
    accs[qq][ch] = s; accq[qq][ch] = q;
    __syncthreads();
    if (threadIdx.x < 64){
        int c = threadIdx.x;
        atomicAdd(&stats[c], (accs[0][c] + accs[1][c]) + (accs[2][c] + accs[3][c]));
    } else if (threadIdx.x < 128){
        int c = threadIdx.x - 64;
        atomicAdd(&stats[64 + c], (accq[0][c] + accq[1][c]) + (accq[2][c] + accq[3][c]));
    }
}

// ---------------- stats2 v3: pk_fma W1 (bitwise-identical accumulation order) ----------------
__global__ __launch_bounds__(256, 1) void stats2_kernel(const float* __restrict__ xyz, const float* __restrict__ pts,
                                                        const float* __restrict__ outc, const u16* __restrict__ gidx,
                                                        const float* __restrict__ W0f, const float* __restrict__ b0f,
                                                        const float* __restrict__ W1f, const float* __restrict__ b1f,
                                                        const float* __restrict__ g0, const float* __restrict__ bb0,
                                                        float* __restrict__ stats){
    __shared__ float sc1[64], sh1[64];
    __shared__ float tr[256 * 65];
    __shared__ float accs[4][64], accq[4][64];
    if (threadIdx.x < 64) bn_coef(stats + 0, stats + 64, g0, bb0, threadIdx.x, sc1, sh1);
    __syncthreads();
    const int row = blockIdx.x * 256 + threadIdx.x;
    float x[9];
    gather_row(xyz, pts, outc, gidx, row, x);
    f32x2 x2p[32];
    #pragma unroll
    for (int j = 0; j < 64; ++j){
        float acc = b0f[j];
        #pragma unroll
        for (int k = 0; k < 9; ++k) acc = fmaf(x[k], W0f[j*9+k], acc);
        float v = fmaxf(fmaf(acc, sc1[j], sh1[j]), 0.f);
        if (j & 1) x2p[j >> 1].y = v; else x2p[j >> 1].x = v;
    }
    // W1: A={a0,a1}, B={a2,a3}; pk pairs (k,k+1)/(k+2,k+3), k+=4 -> same per-acc FMA
    // sequence and same (a0+a1)+(a2+a3) combine as the scalar version: bit-identical.
    for (int ch = 0; ch < 64; ++ch){
        const f32x2* wp = (const f32x2*)(W1f + ch * 64);
        f32x2 A; A.x = b1f[ch]; A.y = 0.f;
        f32x2 B; B.x = 0.f;     B.y = 0.f;
        #pragma unroll
        for (int k2 = 0; k2 < 32; k2 += 2){
            A = pk_fma(x2p[k2],     wp[k2],     A);
            B = pk_fma(x2p[k2 + 1], wp[k2 + 1], B);
        }
        tr[threadIdx.x * 65 + ch] = (A.x + A.y) + (B.x + B.y);
    }
    __syncthreads();
    const int ch = threadIdx.x & 63, qq = threadIdx.x >> 6;
    float s = 0.f, q = 0.f;
    for (int r = 0; r < 64; ++r){
        float v = tr[(qq * 64 + r) * 65 + ch];
        s += v; q = fmaf(v, v, q);
    }
    accs[qq][ch] = s; accq[qq][ch] = q;
    __syncthreads();
    if (threadIdx.x < 64){
        int c = threadIdx.x;
        atomicAdd(&stats[128 + c], (accs[0][c] + accs[1][c]) + (accs[2][c] + accs[3][c]));
    } else if (threadIdx.x < 128){
        int c = threadIdx.x - 64;
        atomicAdd(&stats[192 + c], (accq[0][c] + accq[1][c]) + (accq[2][c] + accq[3][c]));
    }
}

// ---------------- stats3 v3: LDS-staged x3 + pk_fma W1/W2 ----------------
__global__ __launch_bounds__(256, 1) void stats3_kernel(const float* __restrict__ xyz, const float* __restrict__ pts,
                                                        const float* __restrict__ outc, const u16* __restrict__ gidx,
                                                        const float* __restrict__ W0f, const float* __restrict__ b0f,
                                                        const float* __restrict__ W1f, const float* __restrict__ b1f,
                                                        const float* __restrict__ W2f, const float* __restrict__ b2f,
                                                        const float* __restrict__ g0, const float* __restrict__ bb0,
                                                        const float* __restrict__ g1, const float* __restrict__ bb1,
                                                        float* __restrict__ stats,
                                                        float* __restrict__ pmax, float* __restrict__ pmin){
    __shared__ float sc1[64], sh1[64], sc2[64], sh2[64];
    __shared__ float tr[256 * 65];
    __shared__ float accs[4][64], accq[4][64];
    if (threadIdx.x < 64){
        bn_coef(stats + 0,   stats + 64,  g0, bb0, threadIdx.x, sc1, sh1);
        bn_coef(stats + 128, stats + 192, g1, bb1, threadIdx.x, sc2, sh2);
    }
    __syncthreads();
    const int row = blockIdx.x * 256 + threadIdx.x;
    float x[9];
    gather_row(xyz, pts, outc, gidx, row, x);
    f32x2 x2p[32];
    #pragma unroll
    for (int j = 0; j < 64; ++j){
        float acc = b0f[j];
        #pragma unroll
        for (int k = 0; k < 9; ++k) acc = fmaf(x[k], W0f[j*9+k], acc);
        float v = fmaxf(fmaf(acc, sc1[j], sh1[j]), 0.f);
        if (j & 1) x2p[j >> 1].y = v; else x2p[j >> 1].x = v;
    }
    // phase B: x3[j] -> LDS (own row, same-thread RAW; kills x2/x3 dual-liveness spills)
    #pragma unroll
    for (int j = 0; j < 64; ++j){
        const f32x2* wp = (const f32x2*)(W1f + j * 64);
        f32x2 A; A.x = b1f[j]; A.y = 0.f;
        f32x2 B; B.x = 0.f;    B.y = 0.f;
        #pragma unroll
        for (int k2 = 0; k2 < 32; k2 += 2){
            A = pk_fma(x2p[k2],     wp[k2],     A);
            B = pk_fma(x2p[k2 + 1], wp[k2 + 1], B);
        }
        tr[threadIdx.x * 65 + j] = fmaxf(fmaf((A.x + A.y) + (B.x + B.y), sc2[j], sh2[j]), 0.f);
    }
    // compiler barrier: forbid store-to-load forwarding of the staged x3 (which
    // would resurrect the x2+x3 dual-liveness and the spills)
    asm volatile("" ::: "memory");
    f32x2 x3p[32];
    #pragma unroll
    for (int j = 0; j < 32; ++j){
        x3p[j].x = tr[threadIdx.x * 65 + 2*j];
        x3p[j].y = tr[threadIdx.x * 65 + 2*j + 1];
    }
    const int ch = threadIdx.x & 63, qq = threadIdx.x >> 6;
    for (int half = 0; half < 2; ++half){
        for (int c64 = 0; c64 < 64; ++c64){
            int c = half * 64 + c64;
            const f32x2* wp = (const f32x2*)(W2f + c * 64);
            f32x2 A; A.x = b2f[c]; A.y = 0.f;
            f32x2 B; B.x = 0.f;    B.y = 0.f;
            #pragma unroll
            for (int k2 = 0; k2 < 32; k2 += 2){
                A = pk_fma(x3p[k2],     wp[k2],     A);
                B = pk_fma(x3p[k2 + 1], wp[k2 + 1], B);
            }
            tr[threadIdx.x * 65 + c64] = (A.x + A.y) + (B.x + B.y);
        }
        __syncthreads();
        // quarter qq = rows [qq*64, qq*64+64) = groups 2qq (first 32 rows) and 2qq+1
        float s = 0.f, q = 0.f;
        float mxA = -1e30f, mnA = 1e30f, mxB = -1e30f, mnB = 1e30f;
        for (int r = 0; r < 32; ++r){
            float v = tr[(qq * 64 + r) * 65 + ch];
            s += v; q = fmaf(v, v, q);
            mxA = fmaxf(mxA, v); mnA = fminf(mnA, v);
        }
        for (int r = 32; r < 64; ++r){
            float v = tr[(qq * 64 + r) * 65 + ch];
            s += v; q = fmaf(v, v, q);
            mxB = fmaxf(mxB, v); mnB = fminf(mnB, v);
        }
        int c = half * 64 + ch;
        int gA = blockIdx.x * 8 + 2 * qq;
        pmax[(size_t)gA * 128 + c] = mxA;           // coalesced across lanes (c consecutive)
        pmin[(size_t)gA * 128 + c] = mnA;
        pmax[(size_t)(gA + 1) * 128 + c] = mxB;
        pmin[(size_t)(gA + 1) * 128 + c] = mnB;
        accs[qq][ch] = s; accq[qq][ch] = q;
        __syncthreads();
        if (threadIdx.x < 64){
            int cc = half * 64 + threadIdx.x;
            atomicAdd(&stats[256 + cc], (accs[0][threadIdx.x] + accs[1][threadIdx.x])
                                      + (accs[2][threadIdx.x] + accs[3][threadIdx.x]));
        } else if (threadIdx.x < 128){
            int t = threadIdx.x - 64;
            int cc = half * 64 + t;
            atomicAdd(&stats[384 + cc], (accq[0][t] + accq[1][t]) + (accq[2][t] + accq[3][t]));
        }
        __syncthreads();   // tr + accs reuse protection for next half
    }
}

// ---------------- BN3 applied to group max/min, relu, write out region 1 (f32) ----------------
__global__ __launch_bounds__(256) void pool_kernel(const float* __restrict__ stats,
                                                   const float* __restrict__ g2, const float* __restrict__ bb2,
                                                   const float* __restrict__ pmax, const float* __restrict__ pmin,
                                                   float* __restrict__ out){
    __shared__ float sc[128], sh[128];
    if (threadIdx.x < 128) bn_coef(stats + 256, stats + 384, g2, bb2, threadIdx.x, sc, sh);
    __syncthreads();
    int o = blockIdx.x * 256 + threadIdx.x;   // o = g*128 + ch, o < NGRP*128
    int ch = o & 127;
    float a = fmaf(pmax[o], sc[ch], sh[ch]);
    float b = fmaf(pmin[o], sc[ch], sh[ch]);  // affine maps interval endpoints (sc<0 covered)
    out[NGRP * 3 + o] = fmaxf(fmaxf(a, b), 0.0f);
}

extern "C" void kernel_launch(void* const* d_in, const int* in_sizes, int n_in,
                              void* d_out, int out_size, void* d_ws, size_t ws_size,
                              hipStream_t stream){
    const float* xyz = (const float*)d_in[0];
    const float* pts = (const float*)d_in[1];
    const float* W0  = (const float*)d_in[2];
    const float* b0  = (const float*)d_in[3];
    const float* g0  = (const float*)d_in[4];
    const float* bb0 = (const float*)d_in[5];
    const float* W1  = (const float*)d_in[6];
    const float* b1  = (const float*)d_in[7];
    const float* g1  = (const float*)d_in[8];
    const float* bb1 = (const float*)d_in[9];
    const float* W2  = (const float*)d_in[10];
    const float* b2  = (const float*)d_in[11];
    const float* g2  = (const float*)d_in[12];
    const float* bb2 = (const float*)d_in[13];
    float* out = (float*)d_out;   // f32 outputs: [new_xyz 49152 | new_points 2097152]

    // ws layout (bytes): stats[512f]@0 | gidx[524288 u16]@2048 |
    //                    pmax[2097152f]@1050624 | pmin@9439232 ; total 17,827,840
    if (ws_size < 17827840u) return;
    char*  ws    = (char*)d_ws;
    float* stats = (float*)ws;
    u16*   gidx  = (u16*)  (ws + 2048);
    float* pmax  = (float*)(ws + 1050624);
    float* pmin  = (float*)(ws + 9439232);

    fps_kernel  <<<16, 256, 0, stream>>>(xyz, out, stats);   // block 0 also zeroes stats
    ballq_kernel<<<NGRP/4, 256, 0, stream>>>(xyz, out, gidx);
    stats1_kernel<<<ROWS/256, 256, 0, stream>>>(xyz, pts, out, gidx, W0, b0, stats);
    stats2_kernel<<<ROWS/256, 256, 0, stream>>>(xyz, pts, out, gidx, W0, b0, W1, b1, g0, bb0, stats);
    stats3_kernel<<<ROWS/256, 256, 0, stream>>>(xyz, pts, out, gidx, W0, b0, W1, b1, W2, b2,
                                                g0, bb0, g1, bb1, stats, pmax, pmin);
    pool_kernel <<<NGRP*128/256, 256, 0, stream>>>(stats, g2, bb2, pmax, pmin, out);
}